// Round 9
// baseline (680.080 us; speedup 1.0000x reference)
//
#include <hip/hip_runtime.h>

#define U_N 100000
#define I_N 50000
#define D_N 128
#define B_N 4
#define E_N 500000
#define NEDGE (B_N * E_N)            // 2,000,000
#define NKEYU (4 * U_N)              // keys u*4+b
#define NKEYS (NKEYU + 4 * I_N)      // 600,000
#define NMEMB (2 * NEDGE)            // 4,000,000
#define SCHUNK 2048
#define SNBLK ((NKEYS + SCHUNK - 1) / SCHUNK)   // 293
#define TBI ((I_N + 31) / 32)        // transform blocks (item side)
#define TBU ((U_N + 31) / 32)        // transform blocks (user side)
#define NZ4 ((NKEYS + 4) / 4)        // int4 count for offs zeroing
#define ZB  ((NZ4 + 255) / 256)      // zero-role blocks

typedef float f32x2 __attribute__((ext_vector_type(2)));
typedef int   i32x2 __attribute__((ext_vector_type(2)));

// round-to-nearest-even-ish bf16 pack of two floats -> uint (lo=a, hi=b)
__device__ inline unsigned int pack_bf16(float a, float b) {
    unsigned int ua = __float_as_uint(a);
    ua += 0x7FFFu + ((ua >> 16) & 1u);
    unsigned int ub = __float_as_uint(b);
    ub += 0x7FFFu + ((ub >> 16) & 1u);
    return (ua >> 16) | (ub & 0xFFFF0000u);
}

// ---------------------------------------------------------------------------
// Fused: tA = item_emb @ u_w (bf16), tB = user_emb @ i_w (bf16), plus
// zero-role blocks clearing offs[]. One dispatch.
// ---------------------------------------------------------------------------
__global__ __launch_bounds__(256) void transform2_kernel(
    const float* __restrict__ item_emb, const float* __restrict__ user_emb,
    const float* __restrict__ u_w, const float* __restrict__ i_w,
    unsigned int* __restrict__ tA, unsigned int* __restrict__ tB,
    int4* __restrict__ offs4)
{
    __shared__ float wlds[D_N][D_N];

    const float* X; const float* W; unsigned int* Y; int N; int blk;
    if (blockIdx.x < TBI) {
        X = item_emb; W = u_w; Y = tA; N = I_N; blk = blockIdx.x;
    } else if (blockIdx.x < TBI + TBU) {
        X = user_emb; W = i_w; Y = tB; N = U_N; blk = blockIdx.x - TBI;
    } else {
        int t = (blockIdx.x - TBI - TBU) * 256 + threadIdx.x;
        if (t < NZ4) offs4[t] = make_int4(0, 0, 0, 0);
        return;
    }

    for (int idx = threadIdx.x; idx < D_N * D_N / 4; idx += 256)
        reinterpret_cast<float4*>(&wlds[0][0])[idx] =
            reinterpret_cast<const float4*>(W)[idx];
    __syncthreads();

    int rr = threadIdx.x & 31;
    int cg = threadIdx.x >> 5;
    int c0 = cg * 16;
    int r  = blk * 32 + rr;
    bool valid = (r < N);
    int rc = valid ? r : (N - 1);
    const float* xrow = X + (size_t)rc * D_N;

    float4 acc[4];
    #pragma unroll
    for (int c = 0; c < 4; ++c) acc[c] = make_float4(0.f, 0.f, 0.f, 0.f);

    for (int k4 = 0; k4 < D_N / 4; ++k4) {
        float4 a = *reinterpret_cast<const float4*>(xrow + k4 * 4);
        #pragma unroll
        for (int kk = 0; kk < 4; ++kk) {
            float ak = (kk == 0) ? a.x : (kk == 1) ? a.y : (kk == 2) ? a.z : a.w;
            #pragma unroll
            for (int c = 0; c < 4; ++c) {
                const float4 wv = *reinterpret_cast<const float4*>(
                    &wlds[k4 * 4 + kk][c0 + c * 4]);
                acc[c].x += ak * wv.x;
                acc[c].y += ak * wv.y;
                acc[c].z += ak * wv.z;
                acc[c].w += ak * wv.w;
            }
        }
    }
    if (valid) {
        // row r: uint index = r*64 + dim/2; colgroup covers dims c0..c0+15
        unsigned int* yrow = Y + (size_t)r * (D_N / 2) + c0 / 2;
        #pragma unroll
        for (int c = 0; c < 4; ++c) {
            yrow[2 * c]     = pack_bf16(acc[c].x, acc[c].y);
            yrow[2 * c + 1] = pack_bf16(acc[c].z, acc[c].w);
        }
    }
}

// ---------------------------------------------------------------------------
// Count + rank: one membership per thread; atomic return value = rank.
// ---------------------------------------------------------------------------
__global__ __launch_bounds__(256) void count_kernel(
    const int* __restrict__ eu, const int* __restrict__ ei,
    int* __restrict__ offs, int* __restrict__ rank_u, int* __restrict__ rank_i)
{
    int t = blockIdx.x * 256 + threadIdx.x;
    if (t >= NMEMB) return;
    if (t < NEDGE) {
        int e = t;
        int key = eu[e] * 4 + e / E_N;
        rank_u[e] = atomicAdd(&offs[key], 1);
    } else {
        int e = t - NEDGE;
        int key = NKEYU + ei[e] * 4 + e / E_N;
        rank_i[e] = atomicAdd(&offs[key], 1);
    }
}

// ---------------------------------------------------------------------------
// In-place hierarchical exclusive scan over offs[NKEYS].
// ---------------------------------------------------------------------------
__global__ __launch_bounds__(256) void scan1_kernel(
    int* __restrict__ offs, int* __restrict__ bsum)
{
    __shared__ int s[256];
    int base = blockIdx.x * SCHUNK + threadIdx.x * 8;
    int v[8]; int tsum = 0;
    #pragma unroll
    for (int j = 0; j < 8; ++j) {
        int idx = base + j;
        v[j] = (idx < NKEYS) ? offs[idx] : 0;
        tsum += v[j];
    }
    s[threadIdx.x] = tsum; __syncthreads();
    for (int off = 1; off < 256; off <<= 1) {
        int t = (threadIdx.x >= off) ? s[threadIdx.x - off] : 0;
        __syncthreads(); s[threadIdx.x] += t; __syncthreads();
    }
    int excl = s[threadIdx.x] - tsum;
    if (threadIdx.x == 255) bsum[blockIdx.x] = s[255];
    int run = excl;
    #pragma unroll
    for (int j = 0; j < 8; ++j) {
        int idx = base + j;
        if (idx < NKEYS) offs[idx] = run;
        run += v[j];
    }
}

__global__ __launch_bounds__(512) void scan2_kernel(int* __restrict__ bsum,
                                                    int* __restrict__ offs)
{
    __shared__ int s[512];
    int v = (threadIdx.x < SNBLK) ? bsum[threadIdx.x] : 0;
    s[threadIdx.x] = v; __syncthreads();
    for (int off = 1; off < 512; off <<= 1) {
        int t = (threadIdx.x >= off) ? s[threadIdx.x - off] : 0;
        __syncthreads(); s[threadIdx.x] += t; __syncthreads();
    }
    if (threadIdx.x < SNBLK) bsum[threadIdx.x] = s[threadIdx.x] - v;
    if (threadIdx.x == 511) offs[NKEYS] = s[511];
}

__global__ __launch_bounds__(256) void scan3_kernel(int* __restrict__ offs,
                                                    const int* __restrict__ bsum)
{
    int add = bsum[blockIdx.x];
    int base = blockIdx.x * SCHUNK + threadIdx.x * 8;
    #pragma unroll
    for (int j = 0; j < 8; ++j) {
        int idx = base + j;
        if (idx < NKEYS) offs[idx] += add;
    }
}

// ---------------------------------------------------------------------------
// Atomic-free fill: pos = offs[key] + precomputed rank.
// ---------------------------------------------------------------------------
__global__ __launch_bounds__(256) void fill_kernel(
    const int* __restrict__ eu, const int* __restrict__ ei,
    const float* __restrict__ ew,
    const int* __restrict__ offs,
    const int* __restrict__ rank_u, const int* __restrict__ rank_i,
    int2* __restrict__ pairs)
{
    int t = blockIdx.x * 256 + threadIdx.x;
    if (t >= NMEMB) return;
    if (t < NEDGE) {
        int e = t;
        int b = e / E_N;
        int key = eu[e] * 4 + b;
        int pos = offs[key] + rank_u[e];
        pairs[pos] = make_int2(ei[e], __float_as_int(ew[e]));
    } else {
        int e = t - NEDGE;
        int b = e / E_N;
        int key = NKEYU + ei[e] * 4 + b;
        int pos = offs[key] + rank_i[e];
        pairs[pos] = make_int2(eu[e], __float_as_int(ew[e]));
    }
}

// ---------------------------------------------------------------------------
// Fused gather (both sides): one wave per destination row; lane owns 2 dims
// (one uint = 2 bf16 per membership). 4x unroll. NT loads for pairs (stream),
// NT stores for outputs (keep L2 for the bf16 row pool).
// ---------------------------------------------------------------------------
__global__ __launch_bounds__(256) void gather_kernel(
    const unsigned int* __restrict__ tA, const unsigned int* __restrict__ tB,
    const int2* __restrict__ pairs, const int* __restrict__ offs,
    float* __restrict__ single_u, float* __restrict__ multi_u,
    float* __restrict__ single_i, float* __restrict__ multi_i,
    const float* __restrict__ alpha_p)
{
    int rg = blockIdx.x * 4 + (threadIdx.x >> 6);
    if (rg >= U_N + I_N) return;
    bool uside = rg < U_N;
    int r = uside ? rg : rg - U_N;
    const unsigned int* T = uside ? tA : tB;
    float* single  = uside ? single_u : single_i;
    float* multi   = uside ? multi_u : multi_i;
    int N  = uside ? U_N : I_N;
    int k0 = uside ? r * 4 : NKEYU + r * 4;

    float alpha = alpha_p[0];
    int lane = threadIdx.x & 63;
    const unsigned int* Tl = T + lane;   // lane's uint within each 64-uint row

    int beg = offs[k0];
    float mx = 0.f, my = 0.f;
    #pragma unroll
    for (int b = 0; b < 4; ++b) {
        int end = offs[k0 + b + 1];
        float ax = 0.f, ay = 0.f;
        int p = beg;
        for (; p + 3 < end; p += 4) {
            i32x2 q0 = __builtin_nontemporal_load(
                reinterpret_cast<const i32x2*>(pairs + p));
            i32x2 q1 = __builtin_nontemporal_load(
                reinterpret_cast<const i32x2*>(pairs + p + 1));
            i32x2 q2 = __builtin_nontemporal_load(
                reinterpret_cast<const i32x2*>(pairs + p + 2));
            i32x2 q3 = __builtin_nontemporal_load(
                reinterpret_cast<const i32x2*>(pairs + p + 3));
            unsigned int d0 = Tl[(size_t)q0.x * (D_N / 2)];
            unsigned int d1 = Tl[(size_t)q1.x * (D_N / 2)];
            unsigned int d2 = Tl[(size_t)q2.x * (D_N / 2)];
            unsigned int d3 = Tl[(size_t)q3.x * (D_N / 2)];
            float w0 = __int_as_float(q0.y), w1 = __int_as_float(q1.y);
            float w2 = __int_as_float(q2.y), w3 = __int_as_float(q3.y);
            ax += w0 * __uint_as_float(d0 << 16)
                + w1 * __uint_as_float(d1 << 16)
                + w2 * __uint_as_float(d2 << 16)
                + w3 * __uint_as_float(d3 << 16);
            ay += w0 * __uint_as_float(d0 & 0xFFFF0000u)
                + w1 * __uint_as_float(d1 & 0xFFFF0000u)
                + w2 * __uint_as_float(d2 & 0xFFFF0000u)
                + w3 * __uint_as_float(d3 & 0xFFFF0000u);
        }
        for (; p < end; ++p) {
            i32x2 q = __builtin_nontemporal_load(
                reinterpret_cast<const i32x2*>(pairs + p));
            float w = __int_as_float(q.y);
            unsigned int dv = Tl[(size_t)q.x * (D_N / 2)];
            ax += w * __uint_as_float(dv << 16);
            ay += w * __uint_as_float(dv & 0xFFFF0000u);
        }
        mx += ax; my += ay;
        f32x2 o;
        o.x = ax >= 0.f ? ax : alpha * ax;
        o.y = ay >= 0.f ? ay : alpha * ay;
        __builtin_nontemporal_store(o, reinterpret_cast<f32x2*>(
            single + ((size_t)b * N + r) * D_N + lane * 2));
        beg = end;
    }
    mx *= 0.25f; my *= 0.25f;
    f32x2 o;
    o.x = mx >= 0.f ? mx : alpha * mx;
    o.y = my >= 0.f ? my : alpha * my;
    __builtin_nontemporal_store(o, reinterpret_cast<f32x2*>(
        multi + (size_t)r * D_N + lane * 2));
}

extern "C" void kernel_launch(void* const* d_in, const int* in_sizes, int n_in,
                              void* d_out, int out_size, void* d_ws, size_t ws_size,
                              hipStream_t stream) {
    const float* user_emb = (const float*)d_in[0];
    const float* item_emb = (const float*)d_in[1];
    const int*   eu       = (const int*)d_in[2];
    const int*   ei       = (const int*)d_in[3];
    const float* ew       = (const float*)d_in[4];
    const float* u_w      = (const float*)d_in[5];
    const float* i_w      = (const float*)d_in[6];
    const float* alpha    = (const float*)d_in[7];

    float* out      = (float*)d_out;
    float* multi_u  = out;                                      // [U][D]
    float* multi_i  = out + (size_t)U_N * D_N;                  // [I][D]
    float* single_u = out + (size_t)(U_N + I_N) * D_N;          // [B][U][D]
    float* single_i = single_u + (size_t)B_N * U_N * D_N;       // [B][I][D]

    // ranks live in multi_i's slot (consumed by fill; gather writes after).
    int* rank_u = (int*)multi_i;                                // 8 MB
    int* rank_i = rank_u + NEDGE;                               // 8 MB

    // d_ws: offs | bsum | pairs | tA(bf16) | tB(bf16)  (~73 MB)
    int*  offs  = (int*)d_ws;                                   // NKEYS+4
    int*  bsum  = offs + (NKEYS + 4);                           // 512
    int2* pairs = (int2*)((char*)d_ws + ((((NKEYS + 4 + 512) * 4) + 255) & ~255));
    unsigned int* tA = (unsigned int*)(pairs + NMEMB);          // [I][64] 12.8 MB
    unsigned int* tB = tA + (size_t)I_N * (D_N / 2);            // [U][64] 25.6 MB

    transform2_kernel<<<TBI + TBU + ZB, 256, 0, stream>>>(
        item_emb, user_emb, u_w, i_w, tA, tB, (int4*)offs);
    count_kernel<<<(NMEMB + 255) / 256, 256, 0, stream>>>(eu, ei, offs,
                                                          rank_u, rank_i);
    scan1_kernel<<<SNBLK, 256, 0, stream>>>(offs, bsum);
    scan2_kernel<<<1, 512, 0, stream>>>(bsum, offs);
    scan3_kernel<<<SNBLK, 256, 0, stream>>>(offs, bsum);
    fill_kernel<<<(NMEMB + 255) / 256, 256, 0, stream>>>(eu, ei, ew, offs,
                                                         rank_u, rank_i, pairs);

    gather_kernel<<<(U_N + I_N + 3) / 4, 256, 0, stream>>>(
        tA, tB, pairs, offs,
        single_u, multi_u, single_i, multi_i, alpha);
}

// Round 10
// 626.895 us; speedup vs baseline: 1.0848x; 1.0848x over previous
//
#include <hip/hip_runtime.h>

#define U_N 100000
#define I_N 50000
#define D_N 128
#define B_N 4
#define E_N 500000
#define NEDGE (B_N * E_N)            // 2,000,000
#define NKEYU (4 * U_N)              // keys u*4+b
#define NKEYS (NKEYU + 4 * I_N)      // 600,000
#define NMEMB (2 * NEDGE)            // 4,000,000
#define SCHUNK 2048
#define SNBLK ((NKEYS + SCHUNK - 1) / SCHUNK)   // 293
#define TBI ((I_N + 31) / 32)        // transform blocks (item side)
#define TBU ((U_N + 31) / 32)        // transform blocks (user side)
#define NZ4 ((NKEYS + 4) / 4)        // int4 count for offs zeroing
#define ZB  ((NZ4 + 255) / 256)      // zero-role blocks

typedef float f32x2 __attribute__((ext_vector_type(2)));

// round-to-nearest-even-ish bf16 pack of two floats -> uint (lo=a, hi=b)
__device__ inline unsigned int pack_bf16(float a, float b) {
    unsigned int ua = __float_as_uint(a);
    ua += 0x7FFFu + ((ua >> 16) & 1u);
    unsigned int ub = __float_as_uint(b);
    ub += 0x7FFFu + ((ub >> 16) & 1u);
    return (ua >> 16) | (ub & 0xFFFF0000u);
}

// ---------------------------------------------------------------------------
// Fused: tA = item_emb @ u_w (bf16), tB = user_emb @ i_w (bf16), plus
// zero-role blocks clearing offs[]. One dispatch.
// ---------------------------------------------------------------------------
__global__ __launch_bounds__(256) void transform2_kernel(
    const float* __restrict__ item_emb, const float* __restrict__ user_emb,
    const float* __restrict__ u_w, const float* __restrict__ i_w,
    unsigned int* __restrict__ tA, unsigned int* __restrict__ tB,
    int4* __restrict__ offs4)
{
    __shared__ float wlds[D_N][D_N];

    const float* X; const float* W; unsigned int* Y; int N; int blk;
    if (blockIdx.x < TBI) {
        X = item_emb; W = u_w; Y = tA; N = I_N; blk = blockIdx.x;
    } else if (blockIdx.x < TBI + TBU) {
        X = user_emb; W = i_w; Y = tB; N = U_N; blk = blockIdx.x - TBI;
    } else {
        int t = (blockIdx.x - TBI - TBU) * 256 + threadIdx.x;
        if (t < NZ4) offs4[t] = make_int4(0, 0, 0, 0);
        return;
    }

    for (int idx = threadIdx.x; idx < D_N * D_N / 4; idx += 256)
        reinterpret_cast<float4*>(&wlds[0][0])[idx] =
            reinterpret_cast<const float4*>(W)[idx];
    __syncthreads();

    int rr = threadIdx.x & 31;
    int cg = threadIdx.x >> 5;
    int c0 = cg * 16;
    int r  = blk * 32 + rr;
    bool valid = (r < N);
    int rc = valid ? r : (N - 1);
    const float* xrow = X + (size_t)rc * D_N;

    float4 acc[4];
    #pragma unroll
    for (int c = 0; c < 4; ++c) acc[c] = make_float4(0.f, 0.f, 0.f, 0.f);

    for (int k4 = 0; k4 < D_N / 4; ++k4) {
        float4 a = *reinterpret_cast<const float4*>(xrow + k4 * 4);
        #pragma unroll
        for (int kk = 0; kk < 4; ++kk) {
            float ak = (kk == 0) ? a.x : (kk == 1) ? a.y : (kk == 2) ? a.z : a.w;
            #pragma unroll
            for (int c = 0; c < 4; ++c) {
                const float4 wv = *reinterpret_cast<const float4*>(
                    &wlds[k4 * 4 + kk][c0 + c * 4]);
                acc[c].x += ak * wv.x;
                acc[c].y += ak * wv.y;
                acc[c].z += ak * wv.z;
                acc[c].w += ak * wv.w;
            }
        }
    }
    if (valid) {
        unsigned int* yrow = Y + (size_t)r * (D_N / 2) + c0 / 2;
        #pragma unroll
        for (int c = 0; c < 4; ++c) {
            yrow[2 * c]     = pack_bf16(acc[c].x, acc[c].y);
            yrow[2 * c + 1] = pack_bf16(acc[c].z, acc[c].w);
        }
    }
}

// ---------------------------------------------------------------------------
// Count + rank: one membership per thread; atomic return value = rank.
// ---------------------------------------------------------------------------
__global__ __launch_bounds__(256) void count_kernel(
    const int* __restrict__ eu, const int* __restrict__ ei,
    int* __restrict__ offs, int* __restrict__ rank_u, int* __restrict__ rank_i)
{
    int t = blockIdx.x * 256 + threadIdx.x;
    if (t >= NMEMB) return;
    if (t < NEDGE) {
        int e = t;
        int key = eu[e] * 4 + e / E_N;
        rank_u[e] = atomicAdd(&offs[key], 1);
    } else {
        int e = t - NEDGE;
        int key = NKEYU + ei[e] * 4 + e / E_N;
        rank_i[e] = atomicAdd(&offs[key], 1);
    }
}

// ---------------------------------------------------------------------------
// In-place hierarchical exclusive scan over offs[NKEYS].
// ---------------------------------------------------------------------------
__global__ __launch_bounds__(256) void scan1_kernel(
    int* __restrict__ offs, int* __restrict__ bsum)
{
    __shared__ int s[256];
    int base = blockIdx.x * SCHUNK + threadIdx.x * 8;
    int v[8]; int tsum = 0;
    #pragma unroll
    for (int j = 0; j < 8; ++j) {
        int idx = base + j;
        v[j] = (idx < NKEYS) ? offs[idx] : 0;
        tsum += v[j];
    }
    s[threadIdx.x] = tsum; __syncthreads();
    for (int off = 1; off < 256; off <<= 1) {
        int t = (threadIdx.x >= off) ? s[threadIdx.x - off] : 0;
        __syncthreads(); s[threadIdx.x] += t; __syncthreads();
    }
    int excl = s[threadIdx.x] - tsum;
    if (threadIdx.x == 255) bsum[blockIdx.x] = s[255];
    int run = excl;
    #pragma unroll
    for (int j = 0; j < 8; ++j) {
        int idx = base + j;
        if (idx < NKEYS) offs[idx] = run;
        run += v[j];
    }
}

__global__ __launch_bounds__(512) void scan2_kernel(int* __restrict__ bsum,
                                                    int* __restrict__ offs)
{
    __shared__ int s[512];
    int v = (threadIdx.x < SNBLK) ? bsum[threadIdx.x] : 0;
    s[threadIdx.x] = v; __syncthreads();
    for (int off = 1; off < 512; off <<= 1) {
        int t = (threadIdx.x >= off) ? s[threadIdx.x - off] : 0;
        __syncthreads(); s[threadIdx.x] += t; __syncthreads();
    }
    if (threadIdx.x < SNBLK) bsum[threadIdx.x] = s[threadIdx.x] - v;
    if (threadIdx.x == 511) offs[NKEYS] = s[511];
}

__global__ __launch_bounds__(256) void scan3_kernel(int* __restrict__ offs,
                                                    const int* __restrict__ bsum)
{
    int add = bsum[blockIdx.x];
    int base = blockIdx.x * SCHUNK + threadIdx.x * 8;
    #pragma unroll
    for (int j = 0; j < 8; ++j) {
        int idx = base + j;
        if (idx < NKEYS) offs[idx] += add;
    }
}

// ---------------------------------------------------------------------------
// Atomic-free fill: pos = offs[key] + precomputed rank.
// ---------------------------------------------------------------------------
__global__ __launch_bounds__(256) void fill_kernel(
    const int* __restrict__ eu, const int* __restrict__ ei,
    const float* __restrict__ ew,
    const int* __restrict__ offs,
    const int* __restrict__ rank_u, const int* __restrict__ rank_i,
    int2* __restrict__ pairs)
{
    int t = blockIdx.x * 256 + threadIdx.x;
    if (t >= NMEMB) return;
    if (t < NEDGE) {
        int e = t;
        int b = e / E_N;
        int key = eu[e] * 4 + b;
        int pos = offs[key] + rank_u[e];
        pairs[pos] = make_int2(ei[e], __float_as_int(ew[e]));
    } else {
        int e = t - NEDGE;
        int b = e / E_N;
        int key = NKEYU + ei[e] * 4 + b;
        int pos = offs[key] + rank_i[e];
        pairs[pos] = make_int2(eu[e], __float_as_int(ew[e]));
    }
}

// ---------------------------------------------------------------------------
// Fused gather: one wave per destination row; lane owns 2 dims (1 uint of
// 2 bf16 per membership). The 4 behavior buckets advance IN LOCKSTEP as 4
// independent load chains (branchless: dead slots clamp to index 0 with
// w=0) -> ~4x memory-level parallelism vs serial buckets. All control
// values (p, bounds) are wave-uniform -> scalar branches only at the loop.
// NT stores keep L2/L3 for the bf16 row pool.
// ---------------------------------------------------------------------------
__global__ __launch_bounds__(256) void gather_kernel(
    const unsigned int* __restrict__ tA, const unsigned int* __restrict__ tB,
    const int2* __restrict__ pairs, const int* __restrict__ offs,
    float* __restrict__ single_u, float* __restrict__ multi_u,
    float* __restrict__ single_i, float* __restrict__ multi_i,
    const float* __restrict__ alpha_p)
{
    int rg = blockIdx.x * 4 + (threadIdx.x >> 6);
    if (rg >= U_N + I_N) return;
    bool uside = rg < U_N;
    int r = uside ? rg : rg - U_N;
    const unsigned int* T = uside ? tA : tB;
    float* single  = uside ? single_u : single_i;
    float* multi   = uside ? multi_u : multi_i;
    int N  = uside ? U_N : I_N;
    int k0 = uside ? r * 4 : NKEYU + r * 4;

    float alpha = alpha_p[0];
    int lane = threadIdx.x & 63;
    const unsigned int* Tl = T + lane;   // lane's uint within each 64-uint row

    int o0 = offs[k0],     o1 = offs[k0 + 1], o2 = offs[k0 + 2];
    int o3 = offs[k0 + 3], o4 = offs[k0 + 4];
    int p0 = o0, p1 = o1, p2 = o2, p3 = o3;

    float ax0 = 0.f, ay0 = 0.f, ax1 = 0.f, ay1 = 0.f;
    float ax2 = 0.f, ay2 = 0.f, ax3 = 0.f, ay3 = 0.f;

    while ((p0 < o1) | (p1 < o2) | (p2 < o3) | (p3 < o4)) {
        bool a0 = p0 < o1, a1 = p1 < o2, a2 = p2 < o3, a3 = p3 < o4;
        int i0 = a0 ? p0 : 0;
        int i1 = a1 ? p1 : 0;
        int i2 = a2 ? p2 : 0;
        int i3 = a3 ? p3 : 0;
        int2 q0 = pairs[i0];
        int2 q1 = pairs[i1];
        int2 q2 = pairs[i2];
        int2 q3 = pairs[i3];
        unsigned int d0 = Tl[(size_t)q0.x * (D_N / 2)];
        unsigned int d1 = Tl[(size_t)q1.x * (D_N / 2)];
        unsigned int d2 = Tl[(size_t)q2.x * (D_N / 2)];
        unsigned int d3 = Tl[(size_t)q3.x * (D_N / 2)];
        float w0 = a0 ? __int_as_float(q0.y) : 0.f;
        float w1 = a1 ? __int_as_float(q1.y) : 0.f;
        float w2 = a2 ? __int_as_float(q2.y) : 0.f;
        float w3 = a3 ? __int_as_float(q3.y) : 0.f;
        ax0 += w0 * __uint_as_float(d0 << 16);
        ay0 += w0 * __uint_as_float(d0 & 0xFFFF0000u);
        ax1 += w1 * __uint_as_float(d1 << 16);
        ay1 += w1 * __uint_as_float(d1 & 0xFFFF0000u);
        ax2 += w2 * __uint_as_float(d2 << 16);
        ay2 += w2 * __uint_as_float(d2 & 0xFFFF0000u);
        ax3 += w3 * __uint_as_float(d3 << 16);
        ay3 += w3 * __uint_as_float(d3 & 0xFFFF0000u);
        p0 += a0; p1 += a1; p2 += a2; p3 += a3;
    }

    float mx = 0.25f * (ax0 + ax1 + ax2 + ax3);
    float my = 0.25f * (ay0 + ay1 + ay2 + ay3);

    f32x2 o;
    o.x = ax0 >= 0.f ? ax0 : alpha * ax0;
    o.y = ay0 >= 0.f ? ay0 : alpha * ay0;
    __builtin_nontemporal_store(o, reinterpret_cast<f32x2*>(
        single + ((size_t)0 * N + r) * D_N + lane * 2));
    o.x = ax1 >= 0.f ? ax1 : alpha * ax1;
    o.y = ay1 >= 0.f ? ay1 : alpha * ay1;
    __builtin_nontemporal_store(o, reinterpret_cast<f32x2*>(
        single + ((size_t)1 * N + r) * D_N + lane * 2));
    o.x = ax2 >= 0.f ? ax2 : alpha * ax2;
    o.y = ay2 >= 0.f ? ay2 : alpha * ay2;
    __builtin_nontemporal_store(o, reinterpret_cast<f32x2*>(
        single + ((size_t)2 * N + r) * D_N + lane * 2));
    o.x = ax3 >= 0.f ? ax3 : alpha * ax3;
    o.y = ay3 >= 0.f ? ay3 : alpha * ay3;
    __builtin_nontemporal_store(o, reinterpret_cast<f32x2*>(
        single + ((size_t)3 * N + r) * D_N + lane * 2));

    o.x = mx >= 0.f ? mx : alpha * mx;
    o.y = my >= 0.f ? my : alpha * my;
    __builtin_nontemporal_store(o, reinterpret_cast<f32x2*>(
        multi + (size_t)r * D_N + lane * 2));
}

extern "C" void kernel_launch(void* const* d_in, const int* in_sizes, int n_in,
                              void* d_out, int out_size, void* d_ws, size_t ws_size,
                              hipStream_t stream) {
    const float* user_emb = (const float*)d_in[0];
    const float* item_emb = (const float*)d_in[1];
    const int*   eu       = (const int*)d_in[2];
    const int*   ei       = (const int*)d_in[3];
    const float* ew       = (const float*)d_in[4];
    const float* u_w      = (const float*)d_in[5];
    const float* i_w      = (const float*)d_in[6];
    const float* alpha    = (const float*)d_in[7];

    float* out      = (float*)d_out;
    float* multi_u  = out;                                      // [U][D]
    float* multi_i  = out + (size_t)U_N * D_N;                  // [I][D]
    float* single_u = out + (size_t)(U_N + I_N) * D_N;          // [B][U][D]
    float* single_i = single_u + (size_t)B_N * U_N * D_N;       // [B][I][D]

    // ranks live in multi_i's slot (consumed by fill; gather writes after).
    int* rank_u = (int*)multi_i;                                // 8 MB
    int* rank_i = rank_u + NEDGE;                               // 8 MB

    // d_ws: offs | bsum | pairs | tA(bf16) | tB(bf16)  (~73 MB)
    int*  offs  = (int*)d_ws;                                   // NKEYS+4
    int*  bsum  = offs + (NKEYS + 4);                           // 512
    int2* pairs = (int2*)((char*)d_ws + ((((NKEYS + 4 + 512) * 4) + 255) & ~255));
    unsigned int* tA = (unsigned int*)(pairs + NMEMB);          // [I][64] 12.8 MB
    unsigned int* tB = tA + (size_t)I_N * (D_N / 2);            // [U][64] 25.6 MB

    transform2_kernel<<<TBI + TBU + ZB, 256, 0, stream>>>(
        item_emb, user_emb, u_w, i_w, tA, tB, (int4*)offs);
    count_kernel<<<(NMEMB + 255) / 256, 256, 0, stream>>>(eu, ei, offs,
                                                          rank_u, rank_i);
    scan1_kernel<<<SNBLK, 256, 0, stream>>>(offs, bsum);
    scan2_kernel<<<1, 512, 0, stream>>>(bsum, offs);
    scan3_kernel<<<SNBLK, 256, 0, stream>>>(offs, bsum);
    fill_kernel<<<(NMEMB + 255) / 256, 256, 0, stream>>>(eu, ei, ew, offs,
                                                         rank_u, rank_i, pairs);

    gather_kernel<<<(U_N + I_N + 3) / 4, 256, 0, stream>>>(
        tA, tB, pairs, offs,
        single_u, multi_u, single_i, multi_i, alpha);
}

// Round 11
// 553.894 us; speedup vs baseline: 1.2278x; 1.1318x over previous
//
#include <hip/hip_runtime.h>

#define U_N 100000
#define I_N 50000
#define D_N 128
#define B_N 4
#define E_N 500000
#define NEDGE (B_N * E_N)            // 2,000,000
#define NKEYU (4 * U_N)              // keys u*4+b
#define NKEYS (NKEYU + 4 * I_N)      // 600,000
#define NMEMB (2 * NEDGE)            // 4,000,000
#define SCHUNK 2048
#define SNBLK ((NKEYS + SCHUNK - 1) / SCHUNK)   // 293
#define TBI ((I_N + 31) / 32)        // transform blocks (item side)
#define TBU ((U_N + 31) / 32)        // transform blocks (user side)
#define NZ4 ((NKEYS + 4) / 4)        // int4 count for offs zeroing
#define ZB  ((NZ4 + 255) / 256)      // zero-role blocks

typedef float f32x2 __attribute__((ext_vector_type(2)));

// round-to-nearest-even-ish bf16 pack of two floats -> uint (lo=a, hi=b)
__device__ inline unsigned int pack_bf16(float a, float b) {
    unsigned int ua = __float_as_uint(a);
    ua += 0x7FFFu + ((ua >> 16) & 1u);
    unsigned int ub = __float_as_uint(b);
    ub += 0x7FFFu + ((ub >> 16) & 1u);
    return (ua >> 16) | (ub & 0xFFFF0000u);
}

// ---------------------------------------------------------------------------
// Fused: tA = item_emb @ u_w (bf16), tB = user_emb @ i_w (bf16), plus
// zero-role blocks clearing offs[]. One dispatch.
// ---------------------------------------------------------------------------
__global__ __launch_bounds__(256) void transform2_kernel(
    const float* __restrict__ item_emb, const float* __restrict__ user_emb,
    const float* __restrict__ u_w, const float* __restrict__ i_w,
    unsigned int* __restrict__ tA, unsigned int* __restrict__ tB,
    int4* __restrict__ offs4)
{
    __shared__ float wlds[D_N][D_N];

    const float* X; const float* W; unsigned int* Y; int N; int blk;
    if (blockIdx.x < TBI) {
        X = item_emb; W = u_w; Y = tA; N = I_N; blk = blockIdx.x;
    } else if (blockIdx.x < TBI + TBU) {
        X = user_emb; W = i_w; Y = tB; N = U_N; blk = blockIdx.x - TBI;
    } else {
        int t = (blockIdx.x - TBI - TBU) * 256 + threadIdx.x;
        if (t < NZ4) offs4[t] = make_int4(0, 0, 0, 0);
        return;
    }

    for (int idx = threadIdx.x; idx < D_N * D_N / 4; idx += 256)
        reinterpret_cast<float4*>(&wlds[0][0])[idx] =
            reinterpret_cast<const float4*>(W)[idx];
    __syncthreads();

    int rr = threadIdx.x & 31;
    int cg = threadIdx.x >> 5;
    int c0 = cg * 16;
    int r  = blk * 32 + rr;
    bool valid = (r < N);
    int rc = valid ? r : (N - 1);
    const float* xrow = X + (size_t)rc * D_N;

    float4 acc[4];
    #pragma unroll
    for (int c = 0; c < 4; ++c) acc[c] = make_float4(0.f, 0.f, 0.f, 0.f);

    for (int k4 = 0; k4 < D_N / 4; ++k4) {
        float4 a = *reinterpret_cast<const float4*>(xrow + k4 * 4);
        #pragma unroll
        for (int kk = 0; kk < 4; ++kk) {
            float ak = (kk == 0) ? a.x : (kk == 1) ? a.y : (kk == 2) ? a.z : a.w;
            #pragma unroll
            for (int c = 0; c < 4; ++c) {
                const float4 wv = *reinterpret_cast<const float4*>(
                    &wlds[k4 * 4 + kk][c0 + c * 4]);
                acc[c].x += ak * wv.x;
                acc[c].y += ak * wv.y;
                acc[c].z += ak * wv.z;
                acc[c].w += ak * wv.w;
            }
        }
    }
    if (valid) {
        unsigned int* yrow = Y + (size_t)r * (D_N / 2) + c0 / 2;
        #pragma unroll
        for (int c = 0; c < 4; ++c) {
            yrow[2 * c]     = pack_bf16(acc[c].x, acc[c].y);
            yrow[2 * c + 1] = pack_bf16(acc[c].z, acc[c].w);
        }
    }
}

// ---------------------------------------------------------------------------
// Count + rank: one membership per thread; atomic return value = rank.
// ---------------------------------------------------------------------------
__global__ __launch_bounds__(256) void count_kernel(
    const int* __restrict__ eu, const int* __restrict__ ei,
    int* __restrict__ offs, int* __restrict__ rank_u, int* __restrict__ rank_i)
{
    int t = blockIdx.x * 256 + threadIdx.x;
    if (t >= NMEMB) return;
    if (t < NEDGE) {
        int e = t;
        int key = eu[e] * 4 + e / E_N;
        rank_u[e] = atomicAdd(&offs[key], 1);
    } else {
        int e = t - NEDGE;
        int key = NKEYU + ei[e] * 4 + e / E_N;
        rank_i[e] = atomicAdd(&offs[key], 1);
    }
}

// ---------------------------------------------------------------------------
// In-place hierarchical exclusive scan over offs[NKEYS].
// ---------------------------------------------------------------------------
__global__ __launch_bounds__(256) void scan1_kernel(
    int* __restrict__ offs, int* __restrict__ bsum)
{
    __shared__ int s[256];
    int base = blockIdx.x * SCHUNK + threadIdx.x * 8;
    int v[8]; int tsum = 0;
    #pragma unroll
    for (int j = 0; j < 8; ++j) {
        int idx = base + j;
        v[j] = (idx < NKEYS) ? offs[idx] : 0;
        tsum += v[j];
    }
    s[threadIdx.x] = tsum; __syncthreads();
    for (int off = 1; off < 256; off <<= 1) {
        int t = (threadIdx.x >= off) ? s[threadIdx.x - off] : 0;
        __syncthreads(); s[threadIdx.x] += t; __syncthreads();
    }
    int excl = s[threadIdx.x] - tsum;
    if (threadIdx.x == 255) bsum[blockIdx.x] = s[255];
    int run = excl;
    #pragma unroll
    for (int j = 0; j < 8; ++j) {
        int idx = base + j;
        if (idx < NKEYS) offs[idx] = run;
        run += v[j];
    }
}

__global__ __launch_bounds__(512) void scan2_kernel(int* __restrict__ bsum,
                                                    int* __restrict__ offs)
{
    __shared__ int s[512];
    int v = (threadIdx.x < SNBLK) ? bsum[threadIdx.x] : 0;
    s[threadIdx.x] = v; __syncthreads();
    for (int off = 1; off < 512; off <<= 1) {
        int t = (threadIdx.x >= off) ? s[threadIdx.x - off] : 0;
        __syncthreads(); s[threadIdx.x] += t; __syncthreads();
    }
    if (threadIdx.x < SNBLK) bsum[threadIdx.x] = s[threadIdx.x] - v;
    if (threadIdx.x == 511) offs[NKEYS] = s[511];
}

__global__ __launch_bounds__(256) void scan3_kernel(int* __restrict__ offs,
                                                    const int* __restrict__ bsum)
{
    int add = bsum[blockIdx.x];
    int base = blockIdx.x * SCHUNK + threadIdx.x * 8;
    #pragma unroll
    for (int j = 0; j < 8; ++j) {
        int idx = base + j;
        if (idx < NKEYS) offs[idx] += add;
    }
}

// ---------------------------------------------------------------------------
// Atomic-free fill: pos = offs[key] + precomputed rank.
// ---------------------------------------------------------------------------
__global__ __launch_bounds__(256) void fill_kernel(
    const int* __restrict__ eu, const int* __restrict__ ei,
    const float* __restrict__ ew,
    const int* __restrict__ offs,
    const int* __restrict__ rank_u, const int* __restrict__ rank_i,
    int2* __restrict__ pairs)
{
    int t = blockIdx.x * 256 + threadIdx.x;
    if (t >= NMEMB) return;
    if (t < NEDGE) {
        int e = t;
        int b = e / E_N;
        int key = eu[e] * 4 + b;
        int pos = offs[key] + rank_u[e];
        pairs[pos] = make_int2(ei[e], __float_as_int(ew[e]));
    } else {
        int e = t - NEDGE;
        int b = e / E_N;
        int key = NKEYU + ei[e] * 4 + b;
        int pos = offs[key] + rank_i[e];
        pairs[pos] = make_int2(eu[e], __float_as_int(ew[e]));
    }
}

// ---------------------------------------------------------------------------
// Fused gather: one wave per destination row; lane owns 2 dims (1 uint of
// 2 bf16). 4 behavior buckets advance in lockstep (4 independent load
// chains). ALL wave-uniform control (pointers, bounds, pair values, weight
// selects) is pinned to SGPRs via readfirstlane -> SALU, leaving per-lane
// VALU only for: T-row load (uniform base + lane), bf16 decode, 2 FMAs.
// NT stores keep L2/L3 for the bf16 row pool.
// ---------------------------------------------------------------------------
__global__ __launch_bounds__(256) void gather_kernel(
    const unsigned int* __restrict__ tA, const unsigned int* __restrict__ tB,
    const int2* __restrict__ pairs, const int* __restrict__ offs,
    float* __restrict__ single_u, float* __restrict__ multi_u,
    float* __restrict__ single_i, float* __restrict__ multi_i,
    const float* __restrict__ alpha_p)
{
    int rg = blockIdx.x * 4 + (threadIdx.x >> 6);
    if (rg >= U_N + I_N) return;
    bool uside = rg < U_N;
    int r = uside ? rg : rg - U_N;
    const unsigned int* T = uside ? tA : tB;
    float* single  = uside ? single_u : single_i;
    float* multi   = uside ? multi_u : multi_i;
    int N  = uside ? U_N : I_N;
    int k0 = uside ? r * 4 : NKEYU + r * 4;

    float alpha = alpha_p[0];
    int lane = threadIdx.x & 63;

    int o0 = __builtin_amdgcn_readfirstlane(offs[k0]);
    int o1 = __builtin_amdgcn_readfirstlane(offs[k0 + 1]);
    int o2 = __builtin_amdgcn_readfirstlane(offs[k0 + 2]);
    int o3 = __builtin_amdgcn_readfirstlane(offs[k0 + 3]);
    int o4 = __builtin_amdgcn_readfirstlane(offs[k0 + 4]);
    int p0 = o0, p1 = o1, p2 = o2, p3 = o3;

    float ax0 = 0.f, ay0 = 0.f, ax1 = 0.f, ay1 = 0.f;
    float ax2 = 0.f, ay2 = 0.f, ax3 = 0.f, ay3 = 0.f;

    while ((p0 < o1) | (p1 < o2) | (p2 < o3) | (p3 < o4)) {
        int a0 = p0 < o1, a1 = p1 < o2, a2 = p2 < o3, a3 = p3 < o4;
        // clamp dead slots to a valid in-range position (o0 < o4 here)
        int i0 = a0 ? p0 : o0;
        int i1 = a1 ? p1 : o0;
        int i2 = a2 ? p2 : o0;
        int i3 = a3 ? p3 : o0;
        int2 q0 = pairs[i0];
        int2 q1 = pairs[i1];
        int2 q2 = pairs[i2];
        int2 q3 = pairs[i3];
        int sx0 = __builtin_amdgcn_readfirstlane(q0.x);
        int sw0 = __builtin_amdgcn_readfirstlane(q0.y);
        int sx1 = __builtin_amdgcn_readfirstlane(q1.x);
        int sw1 = __builtin_amdgcn_readfirstlane(q1.y);
        int sx2 = __builtin_amdgcn_readfirstlane(q2.x);
        int sw2 = __builtin_amdgcn_readfirstlane(q2.y);
        int sx3 = __builtin_amdgcn_readfirstlane(q3.x);
        int sw3 = __builtin_amdgcn_readfirstlane(q3.y);
        unsigned int d0 = T[(size_t)sx0 * (D_N / 2) + lane];
        unsigned int d1 = T[(size_t)sx1 * (D_N / 2) + lane];
        unsigned int d2 = T[(size_t)sx2 * (D_N / 2) + lane];
        unsigned int d3 = T[(size_t)sx3 * (D_N / 2) + lane];
        float w0 = a0 ? __int_as_float(sw0) : 0.f;
        float w1 = a1 ? __int_as_float(sw1) : 0.f;
        float w2 = a2 ? __int_as_float(sw2) : 0.f;
        float w3 = a3 ? __int_as_float(sw3) : 0.f;
        ax0 += w0 * __uint_as_float(d0 << 16);
        ay0 += w0 * __uint_as_float(d0 & 0xFFFF0000u);
        ax1 += w1 * __uint_as_float(d1 << 16);
        ay1 += w1 * __uint_as_float(d1 & 0xFFFF0000u);
        ax2 += w2 * __uint_as_float(d2 << 16);
        ay2 += w2 * __uint_as_float(d2 & 0xFFFF0000u);
        ax3 += w3 * __uint_as_float(d3 << 16);
        ay3 += w3 * __uint_as_float(d3 & 0xFFFF0000u);
        p0 += a0; p1 += a1; p2 += a2; p3 += a3;
    }

    float mx = 0.25f * (ax0 + ax1 + ax2 + ax3);
    float my = 0.25f * (ay0 + ay1 + ay2 + ay3);

    f32x2 o;
    o.x = ax0 >= 0.f ? ax0 : alpha * ax0;
    o.y = ay0 >= 0.f ? ay0 : alpha * ay0;
    __builtin_nontemporal_store(o, reinterpret_cast<f32x2*>(
        single + ((size_t)0 * N + r) * D_N + lane * 2));
    o.x = ax1 >= 0.f ? ax1 : alpha * ax1;
    o.y = ay1 >= 0.f ? ay1 : alpha * ay1;
    __builtin_nontemporal_store(o, reinterpret_cast<f32x2*>(
        single + ((size_t)1 * N + r) * D_N + lane * 2));
    o.x = ax2 >= 0.f ? ax2 : alpha * ax2;
    o.y = ay2 >= 0.f ? ay2 : alpha * ay2;
    __builtin_nontemporal_store(o, reinterpret_cast<f32x2*>(
        single + ((size_t)2 * N + r) * D_N + lane * 2));
    o.x = ax3 >= 0.f ? ax3 : alpha * ax3;
    o.y = ay3 >= 0.f ? ay3 : alpha * ay3;
    __builtin_nontemporal_store(o, reinterpret_cast<f32x2*>(
        single + ((size_t)3 * N + r) * D_N + lane * 2));

    o.x = mx >= 0.f ? mx : alpha * mx;
    o.y = my >= 0.f ? my : alpha * my;
    __builtin_nontemporal_store(o, reinterpret_cast<f32x2*>(
        multi + (size_t)r * D_N + lane * 2));
}

extern "C" void kernel_launch(void* const* d_in, const int* in_sizes, int n_in,
                              void* d_out, int out_size, void* d_ws, size_t ws_size,
                              hipStream_t stream) {
    const float* user_emb = (const float*)d_in[0];
    const float* item_emb = (const float*)d_in[1];
    const int*   eu       = (const int*)d_in[2];
    const int*   ei       = (const int*)d_in[3];
    const float* ew       = (const float*)d_in[4];
    const float* u_w      = (const float*)d_in[5];
    const float* i_w      = (const float*)d_in[6];
    const float* alpha    = (const float*)d_in[7];

    float* out      = (float*)d_out;
    float* multi_u  = out;                                      // [U][D]
    float* multi_i  = out + (size_t)U_N * D_N;                  // [I][D]
    float* single_u = out + (size_t)(U_N + I_N) * D_N;          // [B][U][D]
    float* single_i = single_u + (size_t)B_N * U_N * D_N;       // [B][I][D]

    // ranks live in multi_i's slot (consumed by fill; gather writes after).
    int* rank_u = (int*)multi_i;                                // 8 MB
    int* rank_i = rank_u + NEDGE;                               // 8 MB

    // d_ws: offs | bsum | pairs | tA(bf16) | tB(bf16)  (~73 MB)
    int*  offs  = (int*)d_ws;                                   // NKEYS+4
    int*  bsum  = offs + (NKEYS + 4);                           // 512
    int2* pairs = (int2*)((char*)d_ws + ((((NKEYS + 4 + 512) * 4) + 255) & ~255));
    unsigned int* tA = (unsigned int*)(pairs + NMEMB);          // [I][64] 12.8 MB
    unsigned int* tB = tA + (size_t)I_N * (D_N / 2);            // [U][64] 25.6 MB

    transform2_kernel<<<TBI + TBU + ZB, 256, 0, stream>>>(
        item_emb, user_emb, u_w, i_w, tA, tB, (int4*)offs);
    count_kernel<<<(NMEMB + 255) / 256, 256, 0, stream>>>(eu, ei, offs,
                                                          rank_u, rank_i);
    scan1_kernel<<<SNBLK, 256, 0, stream>>>(offs, bsum);
    scan2_kernel<<<1, 512, 0, stream>>>(bsum, offs);
    scan3_kernel<<<SNBLK, 256, 0, stream>>>(offs, bsum);
    fill_kernel<<<(NMEMB + 255) / 256, 256, 0, stream>>>(eu, ei, ew, offs,
                                                         rank_u, rank_i, pairs);

    gather_kernel<<<(U_N + I_N + 3) / 4, 256, 0, stream>>>(
        tA, tB, pairs, offs,
        single_u, multi_u, single_i, multi_i, alpha);
}